// Round 4
// baseline (5313.967 us; speedup 1.0000x reference)
//
#include <hip/hip_runtime.h>

// GumbelDecoderEncoder: B=16384, E=256, V=128, T=16, TAU=1.
// Facts exploited (verified PASS R1/R2):
//  * y is exactly one-hot (or 0 for dead rows) -> input matmuls are table
//    lookups Gi[v] = Wih@(Wd2e[:,v]+bd2e)+bih, row 128 = zero-token.
//  * argmax(softmax((l+g)/1)) == argmax(l+g).
//  * Encoder sieve never fires -> reconst = final encoder state.
//  * Decoder NEVER depends on encoder -> split into two kernels; each needs
//    only one 64KB state array in LDS (exactly 65536 B, no >64KB gamble).
// R4 structure: lane=row matvec. Block = 1024 thr (16 waves) = 64 rows;
// wave owns 16 E-units x 3 gates (acc=48 VGPR); h via one ds_read_b32 per k
// (2-way, free); weights wave-uniform (broadcast/scalar loads, reused across
// 64 rows -> 4x less weight traffic than R2). Tokens flow through ws
// ([T+1][B]) which doubles as the cross-wave exchange (same-block global
// coherence after __syncthreads). br/bz folded into token tables at prep.
// R3 lesson: launch_bounds(256,4) -> 64 VGPR cap -> acc spilled to scratch
// (FETCH +38MB). Here: launch_bounds(1024,4) -> 128 VGPR cap, ~110 live.

namespace {
constexpr int kB  = 16384;
constexpr int kE  = 256;
constexpr int kV  = 128;
constexpr int kT  = 16;
constexpr int kG3 = 768;

constexpr int kOffWdhhT  = 0;                       // [256][768] k-major
constexpr int kOffWehhT  = kG3 * kE;                // [256][768]
constexpr int kOffWe2dT  = 2 * kG3 * kE;            // [256][128]
constexpr int kOffDecTab = kOffWe2dT + kV * kE;     // [129][768] (+bih, +bhh r/z)
constexpr int kOffEncTab = kOffDecTab + 129 * kG3;  // [129][768]
constexpr int kOffTok    = kOffEncTab + 129 * kG3;  // int [17][16384]
// total ws use: 624128 floats + 278528 ints = 3.55 MB
}

__device__ __forceinline__ float sigmf(float v) { return 1.0f / (1.0f + expf(-v)); }
__device__ __forceinline__ float gumbelf(float u) {
  return -logf(-logf(u + 1e-10f) + 1e-10f);
}

// ---- prepass 1: k-major transposes of Whh (dec/enc) and We2d ----
__global__ void prep_transpose(const float* __restrict__ dWhh,
                               const float* __restrict__ eWhh,
                               const float* __restrict__ We2d,
                               float* __restrict__ ws) {
  const int n1 = kG3 * kE;
  const int n2 = n1 + kG3 * kE;
  const int n3 = n2 + kV * kE;
  for (int i = blockIdx.x * blockDim.x + threadIdx.x; i < n3;
       i += gridDim.x * blockDim.x) {
    if (i < n1) {
      const int k = i / kG3, j = i - k * kG3;
      ws[i] = dWhh[j * kE + k];
    } else if (i < n2) {
      const int t = i - n1;
      const int k = t / kG3, j = t - k * kG3;
      ws[i] = eWhh[j * kE + k];
    } else {
      const int t = i - n2;
      const int k = t / kV, v = t - k * kV;
      ws[i] = We2d[v * kE + k];
    }
  }
}

// ---- prepass 2: token->gi tables; bih always folded, bhh folded for the
// r,z gates (j<512). v==128 is the zero-token row. ----
__global__ void prep_tables(const float* __restrict__ Wih,
                            const float* __restrict__ Wd2e,
                            const float* __restrict__ bd2e,
                            const float* __restrict__ bih,
                            const float* __restrict__ bhh,
                            float* __restrict__ tab) {
  const int i = blockIdx.x * blockDim.x + threadIdx.x;
  if (i >= 129 * kG3) return;
  const int v = i / kG3, j = i - v * kG3;
  const float* wr = Wih + j * kE;
  float acc = 0.0f;
  if (v < kV) {
    for (int k = 0; k < kE; ++k) acc = fmaf(wr[k], Wd2e[k * kV + v] + bd2e[k], acc);
  } else {
    for (int k = 0; k < kE; ++k) acc = fmaf(wr[k], bd2e[k], acc);
  }
  tab[i] = acc + bih[j] + (j < 2 * kE ? bhh[j] : 0.0f);
}

// gh accumulation, lane=row: acc[j][g] += h[k][lane] * W[k][g*256+u0+j].
// Weight addresses are wave-uniform (u0 via readfirstlane) -> broadcast or
// scalar loads, reused across all 64 rows.
__device__ __forceinline__ void mv64(float acc[16][3],
                                     const float* __restrict__ hbuf,
                                     const float* __restrict__ WT,
                                     const int u0, const int jx) {
#pragma unroll
  for (int j = 0; j < 16; ++j) { acc[j][0] = 0.f; acc[j][1] = 0.f; acc[j][2] = 0.f; }
  const float* wk = WT + u0;
  for (int k = 0; k < kE; ++k) {
    const float hk = hbuf[k * 64 + jx];
    const float4 a0 = *(const float4*)(wk + 0);
    const float4 a1 = *(const float4*)(wk + 4);
    const float4 a2 = *(const float4*)(wk + 8);
    const float4 a3 = *(const float4*)(wk + 12);
    const float4 b0 = *(const float4*)(wk + kE + 0);
    const float4 b1 = *(const float4*)(wk + kE + 4);
    const float4 b2 = *(const float4*)(wk + kE + 8);
    const float4 b3 = *(const float4*)(wk + kE + 12);
    const float4 c0 = *(const float4*)(wk + 2 * kE + 0);
    const float4 c1 = *(const float4*)(wk + 2 * kE + 4);
    const float4 c2 = *(const float4*)(wk + 2 * kE + 8);
    const float4 c3 = *(const float4*)(wk + 2 * kE + 12);
    const float wa[16] = {a0.x, a0.y, a0.z, a0.w, a1.x, a1.y, a1.z, a1.w,
                          a2.x, a2.y, a2.z, a2.w, a3.x, a3.y, a3.z, a3.w};
    const float wb[16] = {b0.x, b0.y, b0.z, b0.w, b1.x, b1.y, b1.z, b1.w,
                          b2.x, b2.y, b2.z, b2.w, b3.x, b3.y, b3.z, b3.w};
    const float wc[16] = {c0.x, c0.y, c0.z, c0.w, c1.x, c1.y, c1.z, c1.w,
                          c2.x, c2.y, c2.z, c2.w, c3.x, c3.y, c3.z, c3.w};
#pragma unroll
    for (int j = 0; j < 16; ++j) {
      acc[j][0] = fmaf(hk, wa[j], acc[j][0]);
      acc[j][1] = fmaf(hk, wb[j], acc[j][1]);
      acc[j][2] = fmaf(hk, wc[j], acc[j][2]);
    }
    wk += kG3;
  }
}

// GRU pointwise, lane=row, this wave's 16 units. Tab rows carry bih (+bhh for
// r,z); bn loaded wave-uniform from bhh. Reads+writes h[u][lane].
__device__ __forceinline__ void pw64(const float acc[16][3],
                                     float* __restrict__ hbuf,
                                     const float* __restrict__ Tab,
                                     const float* __restrict__ bhh,
                                     const int tk, const int u0, const int jx) {
  const float* gp = Tab + tk * kG3 + u0;
#pragma unroll
  for (int j = 0; j < 16; ++j) {
    const float gr = gp[j], gz = gp[kE + j], gn = gp[2 * kE + j];
    const float bn = bhh[2 * kE + u0 + j];          // wave-uniform
    const float ho = hbuf[(u0 + j) * 64 + jx];
    const float rg = sigmf(gr + acc[j][0]);
    const float zg = sigmf(gz + acc[j][1]);
    const float ng = tanhf(gn + rg * (acc[j][2] + bn));
    hbuf[(u0 + j) * 64 + jx] = (1.0f - zg) * ng + zg * ho;
  }
}

// ================= kernel A: full 16-step decode =================
__launch_bounds__(1024, 4)
__global__ void dec_kernel(const float* __restrict__ x,
                           const float* __restrict__ unoise,
                           const float* __restrict__ dbhh,
                           const float* __restrict__ dbe2d,
                           const float* __restrict__ ws,
                           int* __restrict__ tokws,
                           float* __restrict__ out) {
  const float* WT  = ws + kOffWdhhT;
  const float* W2T = ws + kOffWe2dT;
  const float* Tab = ws + kOffDecTab;
  __shared__ float hd[kE * 64];  // 64 KB exactly

  const int tid  = (int)threadIdx.x;
  const int w    = tid >> 6;
  const int jx   = tid & 63;
  const int row0 = (int)blockIdx.x * 64;
  const int u0   = __builtin_amdgcn_readfirstlane(w * 16);

  for (int i = tid; i < 64 * kE; i += 1024) {
    const int r = i >> 8, k = i & (kE - 1);
    hd[k * 64 + r] = x[(size_t)(row0 + r) * kE + k];
  }
  if (tid < 64) tokws[row0 + tid] = kV;  // slot 0: zero-token
  __syncthreads();

  float Nn[4];
  bool alive[4];
#pragma unroll
  for (int q = 0; q < 4; ++q) { Nn[q] = (float)kT; alive[q] = true; }
  const float2 be2 = *(const float2*)(dbe2d + 2 * jx);

  float acc[16][3];
  for (int t = 0; t < kT; ++t) {
    mv64(acc, hd, WT, u0, jx);
    __syncthreads();                                  // hd reads done
    const int tk = tokws[t * kB + row0 + jx];         // prev step's token
    pw64(acc, hd, Tab, dbhh, tk, u0, jx);
    __syncthreads();                                  // hd is h_t

    // logits rows 4w..4w+3, lane covers cols 2jx,2jx+1
    float l0[4] = {0.f, 0.f, 0.f, 0.f}, l1[4] = {0.f, 0.f, 0.f, 0.f};
    const float* wp2 = W2T + 2 * jx;
#pragma unroll 2
    for (int k = 0; k < kE; ++k) {
      const float4 hq = *(const float4*)(&hd[k * 64 + 4 * w]);  // broadcast
      const float2 wv = *(const float2*)wp2;
      wp2 += kV;
      const float hv[4] = {hq.x, hq.y, hq.z, hq.w};
#pragma unroll
      for (int q = 0; q < 4; ++q) {
        l0[q] = fmaf(hv[q], wv.x, l0[q]);
        l1[q] = fmaf(hv[q], wv.y, l1[q]);
      }
    }
    const size_t rbase = (size_t)row0 + 4 * w;
#pragma unroll
    for (int q = 0; q < 4; ++q) {
      const float2 uu =
          *(const float2*)(unoise + ((size_t)t * kB + rbase + q) * kV + 2 * jx);
      const float a0 = l0[q] + be2.x + gumbelf(uu.x);
      const float a1 = l1[q] + be2.y + gumbelf(uu.y);
      float mv; int mi;
      if (a1 > a0) { mv = a1; mi = 2 * jx + 1; } else { mv = a0; mi = 2 * jx; }
#pragma unroll
      for (int off = 32; off >= 1; off >>= 1) {     // first-occurrence argmax
        const float ov = __shfl_xor(mv, off, 64);
        const int   oi = __shfl_xor(mi, off, 64);
        if (ov > mv || (ov == mv && oi < mi)) { mv = ov; mi = oi; }
      }
      const bool ended = (mi == 0);
      if (ended) Nn[q] = fminf(Nn[q], (float)t);
      const bool anew = alive[q] && !ended;
      alive[q] = anew;
      if (jx == 0) tokws[(t + 1) * kB + rbase + q] = anew ? mi : kV;
      float2 pr;
      pr.x = (anew && mi == 2 * jx) ? 1.0f : 0.0f;
      pr.y = (anew && mi == 2 * jx + 1) ? 1.0f : 0.0f;
      *reinterpret_cast<float2*>(out + ((rbase + q) * kT + t) * kV + 2 * jx) = pr;
    }
    __syncthreads();  // tokws visible (vmcnt drained) + hd reads complete
  }

  const size_t uttN = (size_t)kB * kT * kV;
  if (jx == 0) {
#pragma unroll
    for (int q = 0; q < 4; ++q) out[uttN + row0 + 4 * w + q] = Nn[q];
  }
}

// ================= kernel B: full 16-step encode =================
__launch_bounds__(1024, 4)
__global__ void enc_kernel(const float* __restrict__ ebhh,
                           const float* __restrict__ ws,
                           const int* __restrict__ tokws,
                           float* __restrict__ out) {
  const float* WT  = ws + kOffWehhT;
  const float* Tab = ws + kOffEncTab;
  __shared__ float he[kE * 64];  // 64 KB exactly

  const int tid  = (int)threadIdx.x;
  const int w    = tid >> 6;
  const int jx   = tid & 63;
  const int row0 = (int)blockIdx.x * 64;
  const int u0   = __builtin_amdgcn_readfirstlane(w * 16);

  for (int i = tid; i < 64 * kE; i += 1024) he[i] = 0.0f;
  __syncthreads();

  float acc[16][3];
  for (int t = 0; t < kT; ++t) {
    mv64(acc, he, WT, u0, jx);
    __syncthreads();                                  // he reads done
    const int tk = tokws[(t + 1) * kB + row0 + jx];   // token emitted at step t
    pw64(acc, he, Tab, ebhh, tk, u0, jx);
    __syncthreads();                                  // he is state_t
  }

  // reconst = final encoder state (sieve never fires)
  const size_t base = (size_t)kB * kT * kV + kB;
  for (int i = tid; i < 64 * kE; i += 1024) {
    const int r = i >> 8, k = i & (kE - 1);
    out[base + (size_t)(row0 + r) * kE + k] = he[k * 64 + r];
  }
}

extern "C" void kernel_launch(void* const* d_in, const int* in_sizes, int n_in,
                              void* d_out, int out_size, void* d_ws, size_t ws_size,
                              hipStream_t stream) {
  (void)in_sizes; (void)n_in; (void)out_size; (void)ws_size;
  const float* x      = (const float*)d_in[0];
  // d_in[1] = global_idxes (unused by reference)
  const float* unoise = (const float*)d_in[2];
  const float* dWd2e  = (const float*)d_in[3];
  const float* dbd2e  = (const float*)d_in[4];
  const float* dWih   = (const float*)d_in[5];
  const float* dWhh   = (const float*)d_in[6];
  const float* dbih   = (const float*)d_in[7];
  const float* dbhh   = (const float*)d_in[8];
  const float* dWe2d  = (const float*)d_in[9];
  const float* dbe2d  = (const float*)d_in[10];
  const float* eWd2e  = (const float*)d_in[11];
  const float* ebd2e  = (const float*)d_in[12];
  const float* eWih   = (const float*)d_in[13];
  const float* eWhh   = (const float*)d_in[14];
  const float* ebih   = (const float*)d_in[15];
  const float* ebhh   = (const float*)d_in[16];
  float* ws   = (float*)d_ws;
  int* tokws  = (int*)(ws + kOffTok);

  prep_transpose<<<1664, 256, 0, stream>>>(dWhh, eWhh, dWe2d, ws);
  prep_tables<<<(129 * kG3 + 255) / 256, 256, 0, stream>>>(
      dWih, dWd2e, dbd2e, dbih, dbhh, ws + kOffDecTab);
  prep_tables<<<(129 * kG3 + 255) / 256, 256, 0, stream>>>(
      eWih, eWd2e, ebd2e, ebih, ebhh, ws + kOffEncTab);
  dec_kernel<<<kB / 64, 1024, 0, stream>>>(
      x, unoise, dbhh, dbe2d, ws, tokws, (float*)d_out);
  enc_kernel<<<kB / 64, 1024, 0, stream>>>(
      ebhh, ws, tokws, (float*)d_out);
}